// Round 1
// baseline (347.762 us; speedup 1.0000x reference)
//
#include <hip/hip_runtime.h>

// ---------------------------------------------------------------------------
// NNSensorResponse: out[s,t] = sum_{b,n} sigmoid(MLPp(x))*MLPa(x)*mask * gauss(t-z)
// B=4,N=8000 (BN=32000), F_IN=3, HID=128, S=1024, T=1024, sigma runtime (=5.0).
// Strategy: gaussian is band-limited (sigma=5 -> +-31 ticks covers 6.2 sigma);
// bucket electrons into 16 buckets of 64-tick granularity, each bucket owns a
// 128-tick output span covering every member's z+-31. Fused MFMA kernel per
// (s_tile x bucket x ksplit): GEMM1 (hidden[32e x 128k] @ W2[128k x 128s]) ->
// sigmoid*amp epilogue -> LDS transpose -> GEMM2 (resp[128s x 32e] @ G[32e x 128t]).
// ws usage ~17.1 MB.
// ---------------------------------------------------------------------------

#define BN_E   32000
#define HIDW   128
#define S_DIM  1024
#define T_DIM  1024
#define NBKT   16
#define INV_SQRT_2PI 0.3989422804f

typedef __attribute__((ext_vector_type(8))) unsigned short u16x8;
typedef __attribute__((ext_vector_type(8))) __bf16         bf16x8;
typedef __attribute__((ext_vector_type(4))) float          f32x4;

static __device__ __forceinline__ unsigned short f2bf(float f) {
    union { float f; unsigned int u; } v; v.f = f;
    unsigned int r = v.u + 0x7FFFu + ((v.u >> 16) & 1u);   // RNE, inputs finite
    return (unsigned short)(r >> 16);
}

static __device__ __forceinline__ f32x4 mfma16(u16x8 a, u16x8 b, f32x4 c) {
    return __builtin_amdgcn_mfma_f32_16x16x32_bf16(
        __builtin_bit_cast(bf16x8, a), __builtin_bit_cast(bf16x8, b), c, 0, 0, 0);
}

// ---------------- prep kernels ----------------

// hidden layers for both MLPs, bf16 output. grid: BN_E/2 blocks x 256 thr.
__global__ __launch_bounds__(256) void k_hidden(
    const float* __restrict__ x,
    const float* __restrict__ Wp1, const float* __restrict__ bp1,
    const float* __restrict__ Wa1, const float* __restrict__ ba1,
    unsigned short* __restrict__ HpG, unsigned short* __restrict__ HaG) {
    int e = blockIdx.x * 2 + (threadIdx.x >> 7);
    int j = threadIdx.x & 127;
    float x0 = x[e * 3 + 0], x1 = x[e * 3 + 1], x2 = x[e * 3 + 2];
    float hp = x0 * Wp1[j] + x1 * Wp1[HIDW + j] + x2 * Wp1[2 * HIDW + j] + bp1[j];
    float ha = x0 * Wa1[j] + x1 * Wa1[HIDW + j] + x2 * Wa1[2 * HIDW + j] + ba1[j];
    HpG[e * HIDW + j] = f2bf(fmaxf(hp, 0.f));
    HaG[e * HIDW + j] = f2bf(fmaxf(ha, 0.f));
}

// convert W2 matrices to bf16 (layout preserved [k][s]). grid: 512 x 256.
__global__ __launch_bounds__(256) void k_cvtw(
    const float* __restrict__ Wp2, const float* __restrict__ Wa2,
    unsigned short* __restrict__ Wp2b, unsigned short* __restrict__ Wa2b) {
    int g = blockIdx.x * 256 + threadIdx.x;           // < HIDW*S_DIM
    Wp2b[g] = f2bf(Wp2[g]);
    Wa2b[g] = f2bf(Wa2[g]);
}

static __device__ __forceinline__ int bucket_of(float z) {
    int b = (int)floorf((z - 31.f) * (1.f / 64.f));
    return min(max(b, 0), NBKT - 1);
}

__global__ __launch_bounds__(256) void k_count(const float* __restrict__ z, int* meta) {
    int e = blockIdx.x * 256 + threadIdx.x;
    if (e >= BN_E) return;
    atomicAdd(&meta[bucket_of(z[e])], 1);
}

// meta[0..15]=count, meta[16..31]=cursor, meta[32..48]=start
__global__ void k_scan(int* meta) {
    if (threadIdx.x == 0 && blockIdx.x == 0) {
        int s = 0;
        for (int i = 0; i < NBKT; ++i) { meta[32 + i] = s; meta[16 + i] = s; s += meta[i]; }
        meta[48] = s;
    }
}

__global__ __launch_bounds__(256) void k_fill(const float* __restrict__ z,
                                              int* meta, int* __restrict__ list) {
    int e = blockIdx.x * 256 + threadIdx.x;
    if (e >= BN_E) return;
    int pos = atomicAdd(&meta[16 + bucket_of(z[e])], 1);
    list[pos] = e;
}

// ---------------- main fused kernel ----------------
// grid: (8 s_tiles, 16 buckets, 4 ksplit), 256 threads (4 waves).
__global__ __launch_bounds__(256, 2) void k_main(
    const unsigned short* __restrict__ HpG, const unsigned short* __restrict__ HaG,
    const unsigned short* __restrict__ Wp2b, const unsigned short* __restrict__ Wa2b,
    const float* __restrict__ bp2, const float* __restrict__ ba2,
    const float* __restrict__ zg, const float* __restrict__ maskg,
    const float* __restrict__ sigp, const int* __restrict__ meta,
    const int* __restrict__ list, float* __restrict__ out) {

    const int s0    = blockIdx.x * 128;
    const int bk    = blockIdx.y;
    const int tb    = bk * 64;                 // t span [tb, tb+128)
    const int cnt   = meta[bk];
    const int start = meta[32 + bk];
    const int nch   = (cnt + 31) >> 5;
    const int per   = (nch + 3) >> 2;
    const int c0    = blockIdx.z * per;
    const int c1    = min(nch, c0 + per);
    if (c0 >= c1) return;                      // uniform across block, before any barrier

    const int tid = threadIdx.x;
    const int w = tid >> 6, l = tid & 63, q = l >> 4, c = l & 15;

    const float sigma = sigp[0];
    const float coef  = INV_SQRT_2PI / sigma;
    const float nis2  = -1.f / (2.f * sigma * sigma);

    // LDS (padded strides: Hp/Ha 136, G/Rsp 40 -> 2-way bank aliasing only)
    __shared__ __align__(16) unsigned short HpL[32 * 136];
    __shared__ __align__(16) unsigned short HaL[32 * 136];
    __shared__ __align__(16) unsigned short GL[128 * 40];    // [t_local][e]
    __shared__ __align__(16) unsigned short RspL[128 * 40];  // [s_local][e]

    // K-invariant W2 fragments, register resident. B-frag: B[k][n=s].
    u16x8 wP[2][4], wA[2][4];
#pragma unroll
    for (int n = 0; n < 2; ++n) {
        int sg = s0 + w * 32 + n * 16 + c;
#pragma unroll
        for (int ks = 0; ks < 4; ++ks) {
            u16x8 vp, va;
#pragma unroll
            for (int j = 0; j < 8; ++j) {
                int k = ks * 32 + q * 8 + j;
                vp[j] = Wp2b[k * S_DIM + sg];
                va[j] = Wa2b[k * S_DIM + sg];
            }
            wP[n][ks] = vp; wA[n][ks] = va;
        }
    }
    float bp2v[2] = { bp2[s0 + w * 32 + c], bp2[s0 + w * 32 + 16 + c] };
    float ba2v[2] = { ba2[s0 + w * 32 + c], ba2[s0 + w * 32 + 16 + c] };

    const f32x4 z4 = { 0.f, 0.f, 0.f, 0.f };
    f32x4 acc2[2][8];
#pragma unroll
    for (int m = 0; m < 2; ++m)
#pragma unroll
        for (int n8 = 0; n8 < 8; ++n8) acc2[m][n8] = z4;

    for (int ci = c0; ci < c1; ++ci) {
        __syncthreads();
        {   // stage Hp/Ha chunk: 32 electrons x 128 k (bf16)
            int e = tid >> 3, part = tid & 7;
            int li = ci * 32 + e;
            int ev = list[start + min(li, cnt - 1)];     // dup electron for tail; G row=0 kills it
            const uint4* sp = (const uint4*)&HpG[ev * HIDW + part * 16];
            const uint4* sa = (const uint4*)&HaG[ev * HIDW + part * 16];
            uint4* dp = (uint4*)&HpL[e * 136 + part * 16];
            uint4* da = (uint4*)&HaL[e * 136 + part * 16];
            dp[0] = sp[0]; dp[1] = sp[1];
            da[0] = sa[0]; da[1] = sa[1];

            // stage gaussian G[t_local][e], computed once per block
            int te = tid & 31, tg = tid >> 5;
            int li2 = ci * 32 + te;
            int ev2 = list[start + min(li2, cnt - 1)];
            float zz = zg[ev2];
            float cm = (li2 < cnt) ? coef * maskg[ev2] : 0.f;
#pragma unroll
            for (int i = 0; i < 16; ++i) {
                int tl = tg * 16 + i;
                float d = (float)(tb + tl) - zz;
                GL[tl * 40 + te] = f2bf(cm * __expf(d * d * nis2));
            }
        }
        __syncthreads();

        // GEMM1: C1[e][s] = Hp/Ha[e][k] @ W2[k][s]  (M=e 32, N=s 32/wave, K=128)
        f32x4 aP[2][2], aA[2][2];
#pragma unroll
        for (int m = 0; m < 2; ++m)
#pragma unroll
            for (int n = 0; n < 2; ++n) { aP[m][n] = z4; aA[m][n] = z4; }
#pragma unroll
        for (int ks = 0; ks < 4; ++ks) {
            u16x8 hp0 = *(const u16x8*)&HpL[(c)      * 136 + ks * 32 + q * 8];
            u16x8 hp1 = *(const u16x8*)&HpL[(c + 16) * 136 + ks * 32 + q * 8];
            u16x8 ha0 = *(const u16x8*)&HaL[(c)      * 136 + ks * 32 + q * 8];
            u16x8 ha1 = *(const u16x8*)&HaL[(c + 16) * 136 + ks * 32 + q * 8];
#pragma unroll
            for (int n = 0; n < 2; ++n) {
                aP[0][n] = mfma16(hp0, wP[n][ks], aP[0][n]);
                aP[1][n] = mfma16(hp1, wP[n][ks], aP[1][n]);
                aA[0][n] = mfma16(ha0, wA[n][ks], aA[0][n]);
                aA[1][n] = mfma16(ha1, wA[n][ks], aA[1][n]);
            }
        }

        // epilogue1: rsp = sigmoid(p + bp2) * (a + ba2); C-layout -> RspL[s][e] (wave-private rows)
#pragma unroll
        for (int m = 0; m < 2; ++m)
#pragma unroll
            for (int n = 0; n < 2; ++n) {
                f32x4 p = aP[m][n], a = aA[m][n];
                unsigned long long pk = 0;
#pragma unroll
                for (int r = 0; r < 4; ++r) {
                    float pr = p[r] + bp2v[n];
                    float ar = a[r] + ba2v[n];
                    float sg = __builtin_amdgcn_rcpf(1.f + __expf(-pr));
                    pk |= (unsigned long long)f2bf(sg * ar) << (16 * r);
                }
                int sl = w * 32 + n * 16 + c;        // col of C1 = s
                int e0 = m * 16 + q * 4;             // row of C1 = e (4 consecutive regs)
                *(unsigned long long*)&RspL[sl * 40 + e0] = pk;
            }

        // GEMM2: out[s][t] += Rsp[s][e] @ G[e][t]  (M=s 32/wave, N=t 128, K=32)
        u16x8 bfr[8];
#pragma unroll
        for (int n8 = 0; n8 < 8; ++n8)
            bfr[n8] = *(const u16x8*)&GL[(n8 * 16 + c) * 40 + q * 8];
#pragma unroll
        for (int m = 0; m < 2; ++m) {
            u16x8 afr = *(const u16x8*)&RspL[(w * 32 + m * 16 + c) * 40 + q * 8];
#pragma unroll
            for (int n8 = 0; n8 < 8; ++n8)
                acc2[m][n8] = mfma16(afr, bfr[n8], acc2[m][n8]);
        }
    }

    // epilogue2: atomic accumulate into out (bucket spans overlap + ksplit)
#pragma unroll
    for (int m = 0; m < 2; ++m)
#pragma unroll
        for (int n8 = 0; n8 < 8; ++n8) {
            int t = tb + n8 * 16 + c;
            if (t < T_DIM) {
                int srow = s0 + w * 32 + m * 16 + q * 4;
#pragma unroll
                for (int r = 0; r < 4; ++r)
                    atomicAdd(&out[(srow + r) * T_DIM + t], acc2[m][n8][r]);
            }
        }
}

// ---------------- launch ----------------

extern "C" void kernel_launch(void* const* d_in, const int* in_sizes, int n_in,
                              void* d_out, int out_size, void* d_ws, size_t ws_size,
                              hipStream_t stream) {
    const float* x    = (const float*)d_in[0];
    const float* zp   = (const float*)d_in[1];
    const float* mask = (const float*)d_in[2];
    const float* Wp1  = (const float*)d_in[3];
    const float* bp1  = (const float*)d_in[4];
    const float* Wp2  = (const float*)d_in[5];
    const float* bp2  = (const float*)d_in[6];
    const float* Wa1  = (const float*)d_in[7];
    const float* ba1  = (const float*)d_in[8];
    const float* Wa2  = (const float*)d_in[9];
    const float* ba2  = (const float*)d_in[10];
    const float* sig  = (const float*)d_in[11];

    char* ws = (char*)d_ws;
    unsigned short* HpG  = (unsigned short*)(ws);                      //  8,192,000 B
    unsigned short* HaG  = (unsigned short*)(ws + 8192000);            //  8,192,000 B
    unsigned short* Wp2b = (unsigned short*)(ws + 16384000);           //    262,144 B
    unsigned short* Wa2b = (unsigned short*)(ws + 16646144);           //    262,144 B
    int*            meta = (int*)(ws + 16908288);                      //        256 B
    int*            list = (int*)(ws + 16908544);                      //    128,000 B

    hipMemsetAsync(meta, 0, 256, stream);
    hipMemsetAsync(d_out, 0, (size_t)S_DIM * T_DIM * sizeof(float), stream);

    k_hidden<<<BN_E / 2, 256, 0, stream>>>(x, Wp1, bp1, Wa1, ba1, HpG, HaG);
    k_cvtw<<<(HIDW * S_DIM) / 256, 256, 0, stream>>>(Wp2, Wa2, Wp2b, Wa2b);
    k_count<<<(BN_E + 255) / 256, 256, 0, stream>>>(zp, meta);
    k_scan<<<1, 64, 0, stream>>>(meta);
    k_fill<<<(BN_E + 255) / 256, 256, 0, stream>>>(zp, meta, list);

    k_main<<<dim3(8, NBKT, 4), 256, 0, stream>>>(
        HpG, HaG, Wp2b, Wa2b, bp2, ba2, zp, mask, sig, meta, list, (float*)d_out);
}

// Round 2
// 178.807 us; speedup vs baseline: 1.9449x; 1.9449x over previous
//
#include <hip/hip_runtime.h>

// ---------------------------------------------------------------------------
// NNSensorResponse: out[s,t] = sum_{b,n} sigmoid(MLPp(x))*MLPa(x)*mask * gauss(t-z)
// B=4,N=8000 (BN=32000), F_IN=3, HID=128, S=1024, T=1024, sigma runtime (=5.0).
// Gaussian is band-limited (sigma=5 -> +-31 ticks ~ 6.2 sigma): bucket electrons
// into 16 buckets of 64-tick granularity; each bucket owns a 128-tick span.
// Fused MFMA kernel per (s_tile x bucket x ksplit): GEMM1 (hidden @ W2) ->
// sigmoid*amp epilogue -> LDS transpose -> GEMM2 (resp @ gaussian).
// R2: counting sort via per-block LDS histograms (was: 64k contended global
// atomics on 16 addresses -> 2x 89 us; now zero global atomics in sort).
// ---------------------------------------------------------------------------

#define BN_E   32000
#define NBLK   125          // BN_E / 256
#define HIDW   128
#define S_DIM  1024
#define T_DIM  1024
#define NBKT   16
#define INV_SQRT_2PI 0.3989422804f

typedef __attribute__((ext_vector_type(8))) unsigned short u16x8;
typedef __attribute__((ext_vector_type(8))) __bf16         bf16x8;
typedef __attribute__((ext_vector_type(4))) float          f32x4;

static __device__ __forceinline__ unsigned short f2bf(float f) {
    union { float f; unsigned int u; } v; v.f = f;
    unsigned int r = v.u + 0x7FFFu + ((v.u >> 16) & 1u);   // RNE, inputs finite
    return (unsigned short)(r >> 16);
}

static __device__ __forceinline__ f32x4 mfma16(u16x8 a, u16x8 b, f32x4 c) {
    return __builtin_amdgcn_mfma_f32_16x16x32_bf16(
        __builtin_bit_cast(bf16x8, a), __builtin_bit_cast(bf16x8, b), c, 0, 0, 0);
}

// ---------------- prep kernels ----------------

// hidden layers for both MLPs, bf16 output. grid: BN_E/2 blocks x 256 thr.
__global__ __launch_bounds__(256) void k_hidden(
    const float* __restrict__ x,
    const float* __restrict__ Wp1, const float* __restrict__ bp1,
    const float* __restrict__ Wa1, const float* __restrict__ ba1,
    unsigned short* __restrict__ HpG, unsigned short* __restrict__ HaG) {
    int e = blockIdx.x * 2 + (threadIdx.x >> 7);
    int j = threadIdx.x & 127;
    float x0 = x[e * 3 + 0], x1 = x[e * 3 + 1], x2 = x[e * 3 + 2];
    float hp = x0 * Wp1[j] + x1 * Wp1[HIDW + j] + x2 * Wp1[2 * HIDW + j] + bp1[j];
    float ha = x0 * Wa1[j] + x1 * Wa1[HIDW + j] + x2 * Wa1[2 * HIDW + j] + ba1[j];
    HpG[e * HIDW + j] = f2bf(fmaxf(hp, 0.f));
    HaG[e * HIDW + j] = f2bf(fmaxf(ha, 0.f));
}

// convert W2 matrices to bf16 (layout preserved [k][s]). grid: 512 x 256.
__global__ __launch_bounds__(256) void k_cvtw(
    const float* __restrict__ Wp2, const float* __restrict__ Wa2,
    unsigned short* __restrict__ Wp2b, unsigned short* __restrict__ Wa2b) {
    int g = blockIdx.x * 256 + threadIdx.x;           // < HIDW*S_DIM
    Wp2b[g] = f2bf(Wp2[g]);
    Wa2b[g] = f2bf(Wa2[g]);
}

static __device__ __forceinline__ int bucket_of(float z) {
    int b = (int)floorf((z - 31.f) * (1.f / 64.f));
    return min(max(b, 0), NBKT - 1);
}

// per-block LDS histogram -> blockCounts[blk][16]. grid: NBLK x 256.
__global__ __launch_bounds__(256) void k_count_blk(const float* __restrict__ z,
                                                   int* __restrict__ bc) {
    __shared__ int h[NBKT];
    if (threadIdx.x < NBKT) h[threadIdx.x] = 0;
    __syncthreads();
    int e = blockIdx.x * 256 + threadIdx.x;           // BN_E % 256 == 0
    atomicAdd(&h[bucket_of(z[e])], 1);
    __syncthreads();
    if (threadIdx.x < NBKT) bc[blockIdx.x * NBKT + threadIdx.x] = h[threadIdx.x];
}

// meta[0..15]=count, meta[32..47]=start; base[blk][b] = intra-bucket block base.
__global__ void k_scan2(const int* __restrict__ bc, int* meta, int* __restrict__ base) {
    int b = threadIdx.x;
    if (b < NBKT) {
        int run = 0;
        for (int blk = 0; blk < NBLK; ++blk) {
            base[blk * NBKT + b] = run;
            run += bc[blk * NBKT + b];
        }
        meta[b] = run;
    }
    __syncthreads();
    if (threadIdx.x == 0) {
        int s = 0;
        for (int i = 0; i < NBKT; ++i) { meta[32 + i] = s; s += meta[i]; }
    }
}

// deterministic scatter using LDS ranks. grid: NBLK x 256.
__global__ __launch_bounds__(256) void k_fill_blk(const float* __restrict__ z,
                                                  const int* __restrict__ meta,
                                                  const int* __restrict__ base,
                                                  int* __restrict__ list) {
    __shared__ int h[NBKT];
    if (threadIdx.x < NBKT) h[threadIdx.x] = 0;
    __syncthreads();
    int e = blockIdx.x * 256 + threadIdx.x;
    int b = bucket_of(z[e]);
    int r = atomicAdd(&h[b], 1);
    list[meta[32 + b] + base[blockIdx.x * NBKT + b] + r] = e;
}

// ---------------- main fused kernel ----------------
// grid: (8 s_tiles, 16 buckets, 4 ksplit), 256 threads (4 waves).
__global__ __launch_bounds__(256, 2) void k_main(
    const unsigned short* __restrict__ HpG, const unsigned short* __restrict__ HaG,
    const unsigned short* __restrict__ Wp2b, const unsigned short* __restrict__ Wa2b,
    const float* __restrict__ bp2, const float* __restrict__ ba2,
    const float* __restrict__ zg, const float* __restrict__ maskg,
    const float* __restrict__ sigp, const int* __restrict__ meta,
    const int* __restrict__ list, float* __restrict__ out) {

    const int s0    = blockIdx.x * 128;
    const int bk    = blockIdx.y;
    const int tb    = bk * 64;                 // t span [tb, tb+128)
    const int cnt   = meta[bk];
    const int start = meta[32 + bk];
    const int nch   = (cnt + 31) >> 5;
    const int per   = (nch + 3) >> 2;
    const int c0    = blockIdx.z * per;
    const int c1    = min(nch, c0 + per);
    if (c0 >= c1) return;                      // uniform across block, before any barrier

    const int tid = threadIdx.x;
    const int w = tid >> 6, l = tid & 63, q = l >> 4, c = l & 15;

    const float sigma = sigp[0];
    const float coef  = INV_SQRT_2PI / sigma;
    const float nis2  = -1.f / (2.f * sigma * sigma);

    // LDS (padded strides: Hp/Ha 136, G/Rsp 40 -> 2-way bank aliasing only)
    __shared__ __align__(16) unsigned short HpL[32 * 136];
    __shared__ __align__(16) unsigned short HaL[32 * 136];
    __shared__ __align__(16) unsigned short GL[128 * 40];    // [t_local][e]
    __shared__ __align__(16) unsigned short RspL[128 * 40];  // [s_local][e]

    // K-invariant W2 fragments, register resident. B-frag: B[k][n=s].
    u16x8 wP[2][4], wA[2][4];
#pragma unroll
    for (int n = 0; n < 2; ++n) {
        int sg = s0 + w * 32 + n * 16 + c;
#pragma unroll
        for (int ks = 0; ks < 4; ++ks) {
            u16x8 vp, va;
#pragma unroll
            for (int j = 0; j < 8; ++j) {
                int k = ks * 32 + q * 8 + j;
                vp[j] = Wp2b[k * S_DIM + sg];
                va[j] = Wa2b[k * S_DIM + sg];
            }
            wP[n][ks] = vp; wA[n][ks] = va;
        }
    }
    float bp2v[2] = { bp2[s0 + w * 32 + c], bp2[s0 + w * 32 + 16 + c] };
    float ba2v[2] = { ba2[s0 + w * 32 + c], ba2[s0 + w * 32 + 16 + c] };

    const f32x4 z4 = { 0.f, 0.f, 0.f, 0.f };
    f32x4 acc2[2][8];
#pragma unroll
    for (int m = 0; m < 2; ++m)
#pragma unroll
        for (int n8 = 0; n8 < 8; ++n8) acc2[m][n8] = z4;

    for (int ci = c0; ci < c1; ++ci) {
        __syncthreads();
        {   // stage Hp/Ha chunk: 32 electrons x 128 k (bf16)
            int e = tid >> 3, part = tid & 7;
            int li = ci * 32 + e;
            int ev = list[start + min(li, cnt - 1)];     // dup electron for tail; G row=0 kills it
            const uint4* sp = (const uint4*)&HpG[ev * HIDW + part * 16];
            const uint4* sa = (const uint4*)&HaG[ev * HIDW + part * 16];
            uint4* dp = (uint4*)&HpL[e * 136 + part * 16];
            uint4* da = (uint4*)&HaL[e * 136 + part * 16];
            dp[0] = sp[0]; dp[1] = sp[1];
            da[0] = sa[0]; da[1] = sa[1];

            // stage gaussian G[t_local][e], computed once per block
            int te = tid & 31, tg = tid >> 5;
            int li2 = ci * 32 + te;
            int ev2 = list[start + min(li2, cnt - 1)];
            float zz = zg[ev2];
            float cm = (li2 < cnt) ? coef * maskg[ev2] : 0.f;
#pragma unroll
            for (int i = 0; i < 16; ++i) {
                int tl = tg * 16 + i;
                float d = (float)(tb + tl) - zz;
                GL[tl * 40 + te] = f2bf(cm * __expf(d * d * nis2));
            }
        }
        __syncthreads();

        // GEMM1: C1[e][s] = Hp/Ha[e][k] @ W2[k][s]  (M=e 32, N=s 32/wave, K=128)
        f32x4 aP[2][2], aA[2][2];
#pragma unroll
        for (int m = 0; m < 2; ++m)
#pragma unroll
            for (int n = 0; n < 2; ++n) { aP[m][n] = z4; aA[m][n] = z4; }
#pragma unroll
        for (int ks = 0; ks < 4; ++ks) {
            u16x8 hp0 = *(const u16x8*)&HpL[(c)      * 136 + ks * 32 + q * 8];
            u16x8 hp1 = *(const u16x8*)&HpL[(c + 16) * 136 + ks * 32 + q * 8];
            u16x8 ha0 = *(const u16x8*)&HaL[(c)      * 136 + ks * 32 + q * 8];
            u16x8 ha1 = *(const u16x8*)&HaL[(c + 16) * 136 + ks * 32 + q * 8];
#pragma unroll
            for (int n = 0; n < 2; ++n) {
                aP[0][n] = mfma16(hp0, wP[n][ks], aP[0][n]);
                aP[1][n] = mfma16(hp1, wP[n][ks], aP[1][n]);
                aA[0][n] = mfma16(ha0, wA[n][ks], aA[0][n]);
                aA[1][n] = mfma16(ha1, wA[n][ks], aA[1][n]);
            }
        }

        // epilogue1: rsp = sigmoid(p + bp2) * (a + ba2); C-layout -> RspL[s][e] (wave-private rows)
#pragma unroll
        for (int m = 0; m < 2; ++m)
#pragma unroll
            for (int n = 0; n < 2; ++n) {
                f32x4 p = aP[m][n], a = aA[m][n];
                unsigned long long pk = 0;
#pragma unroll
                for (int r = 0; r < 4; ++r) {
                    float pr = p[r] + bp2v[n];
                    float ar = a[r] + ba2v[n];
                    float sg = __builtin_amdgcn_rcpf(1.f + __expf(-pr));
                    pk |= (unsigned long long)f2bf(sg * ar) << (16 * r);
                }
                int sl = w * 32 + n * 16 + c;        // col of C1 = s
                int e0 = m * 16 + q * 4;             // row of C1 = e (4 consecutive regs)
                *(unsigned long long*)&RspL[sl * 40 + e0] = pk;
            }

        // GEMM2: out[s][t] += Rsp[s][e] @ G[e][t]  (M=s 32/wave, N=t 128, K=32)
        u16x8 bfr[8];
#pragma unroll
        for (int n8 = 0; n8 < 8; ++n8)
            bfr[n8] = *(const u16x8*)&GL[(n8 * 16 + c) * 40 + q * 8];
#pragma unroll
        for (int m = 0; m < 2; ++m) {
            u16x8 afr = *(const u16x8*)&RspL[(w * 32 + m * 16 + c) * 40 + q * 8];
#pragma unroll
            for (int n8 = 0; n8 < 8; ++n8)
                acc2[m][n8] = mfma16(afr, bfr[n8], acc2[m][n8]);
        }
    }

    // epilogue2: atomic accumulate into out (bucket spans overlap + ksplit)
#pragma unroll
    for (int m = 0; m < 2; ++m)
#pragma unroll
        for (int n8 = 0; n8 < 8; ++n8) {
            int t = tb + n8 * 16 + c;
            if (t < T_DIM) {
                int srow = s0 + w * 32 + m * 16 + q * 4;
#pragma unroll
                for (int r = 0; r < 4; ++r)
                    atomicAdd(&out[(srow + r) * T_DIM + t], acc2[m][n8][r]);
            }
        }
}

// ---------------- launch ----------------

extern "C" void kernel_launch(void* const* d_in, const int* in_sizes, int n_in,
                              void* d_out, int out_size, void* d_ws, size_t ws_size,
                              hipStream_t stream) {
    const float* x    = (const float*)d_in[0];
    const float* zp   = (const float*)d_in[1];
    const float* mask = (const float*)d_in[2];
    const float* Wp1  = (const float*)d_in[3];
    const float* bp1  = (const float*)d_in[4];
    const float* Wp2  = (const float*)d_in[5];
    const float* bp2  = (const float*)d_in[6];
    const float* Wa1  = (const float*)d_in[7];
    const float* ba1  = (const float*)d_in[8];
    const float* Wa2  = (const float*)d_in[9];
    const float* ba2  = (const float*)d_in[10];
    const float* sig  = (const float*)d_in[11];

    char* ws = (char*)d_ws;
    unsigned short* HpG  = (unsigned short*)(ws);                      //  8,192,000 B
    unsigned short* HaG  = (unsigned short*)(ws + 8192000);            //  8,192,000 B
    unsigned short* Wp2b = (unsigned short*)(ws + 16384000);           //    262,144 B
    unsigned short* Wa2b = (unsigned short*)(ws + 16646144);           //    262,144 B
    int*            meta = (int*)(ws + 16908288);                      //        256 B
    int*            list = (int*)(ws + 16908544);                      //    128,000 B
    int*            bc   = (int*)(ws + 17036544);                      //      8,000 B
    int*            base = (int*)(ws + 17044544);                      //      8,000 B

    hipMemsetAsync(d_out, 0, (size_t)S_DIM * T_DIM * sizeof(float), stream);

    k_hidden<<<BN_E / 2, 256, 0, stream>>>(x, Wp1, bp1, Wa1, ba1, HpG, HaG);
    k_cvtw<<<(HIDW * S_DIM) / 256, 256, 0, stream>>>(Wp2, Wa2, Wp2b, Wa2b);
    k_count_blk<<<NBLK, 256, 0, stream>>>(zp, bc);
    k_scan2<<<1, 64, 0, stream>>>(bc, meta, base);
    k_fill_blk<<<NBLK, 256, 0, stream>>>(zp, meta, base, list);

    k_main<<<dim3(8, NBKT, 4), 256, 0, stream>>>(
        HpG, HaG, Wp2b, Wa2b, bp2, ba2, zp, mask, sig, meta, list, (float*)d_out);
}